// Round 2
// baseline (81.117 us; speedup 1.0000x reference)
//
#include <hip/hip_runtime.h>
#include <stdint.h>

// SimpleRouter: forward output depends ONLY on jax.random.normal(key(42), (16384,256)).
// The gate GEMM is erased by the straight-through estimator (value = rand).
// Modern JAX default: jax_threefry_partitionable=True ->
//   bits[i] = y0 ^ y1 of threefry2x32(key=(0,42), x0=hi32(i)=0, x1=lo32(i)=i)

#define NTOK 16384
#define NEXP 256
#define TOPK 8

__device__ __forceinline__ uint32_t rotl32(uint32_t v, int r) {
  return (v << r) | (v >> (32 - r));
}

// Partitionable-threefry 32-bit random word for flat index i, key (0, 42).
__device__ __forceinline__ uint32_t threefry_bits_k42(uint32_t i) {
  const uint32_t ks0 = 0u;
  const uint32_t ks1 = 42u;
  const uint32_t ks2 = 0x1BD11BF0u;  // 0 ^ 42 ^ 0x1BD11BDA
  uint32_t x0 = ks0;        // counts_hi = 0, + ks0
  uint32_t x1 = i + ks1;    // counts_lo = i, + ks1
#define QR(R) x0 += x1; x1 = rotl32(x1, R); x1 ^= x0;
  QR(13) QR(15) QR(26) QR(6)
  x0 += ks1; x1 += ks2 + 1u;
  QR(17) QR(29) QR(16) QR(24)
  x0 += ks2; x1 += ks0 + 2u;
  QR(13) QR(15) QR(26) QR(6)
  x0 += ks0; x1 += ks1 + 3u;
  QR(17) QR(29) QR(16) QR(24)
  x0 += ks1; x1 += ks2 + 4u;
  QR(13) QR(15) QR(26) QR(6)
  x0 += ks2; x1 += ks0 + 5u;
#undef QR
  return x0 ^ x1;   // 32-bit fold of the two output words
}

// bits -> sigmoid(sqrt(2)*erfinv(uniform(lo,1))) following XLA CPU lowerings,
// explicit round-to-nearest ops to forbid FMA contraction (XLA CPU emits
// separate fmul/fadd with contraction off).
__device__ __forceinline__ float score_from_bits(uint32_t bits) {
  float f = __uint_as_float((bits >> 9) | 0x3f800000u);
  f = __fadd_rn(f, -1.0f);                        // in [0,1)
  const float lo = __uint_as_float(0xBF7FFFFFu);  // nextafter(-1,0)
  float u = fmaxf(lo, __fadd_rn(__fmul_rn(f, 2.0f), lo));  // hi-lo == 2.0f exactly

  // w = -log1p(-u*u); XLA log1p: |x|<1e-4 ? x*(1-0.5x) : log(1+x)
  float negxx = -__fmul_rn(u, u);
  float w;
  if (fabsf(negxx) < 1e-4f) {
    w = -__fmul_rn(__fadd_rn(__fmul_rn(-0.5f, negxx), 1.0f), negxx);
  } else {
    w = -logf(__fadd_rn(1.0f, negxx));
  }

  float p;
  if (w < 5.0f) {
    float t = __fadd_rn(w, -2.5f);
    p = 2.81022636e-08f;
    p = __fadd_rn(3.43273939e-07f,  __fmul_rn(p, t));
    p = __fadd_rn(-3.5233877e-06f,  __fmul_rn(p, t));
    p = __fadd_rn(-4.39150654e-06f, __fmul_rn(p, t));
    p = __fadd_rn(0.00021858087f,   __fmul_rn(p, t));
    p = __fadd_rn(-0.00125372503f,  __fmul_rn(p, t));
    p = __fadd_rn(-0.00417768164f,  __fmul_rn(p, t));
    p = __fadd_rn(0.246640727f,     __fmul_rn(p, t));
    p = __fadd_rn(1.50140941f,      __fmul_rn(p, t));
  } else {
    float t = __fadd_rn(__fsqrt_rn(w), -3.0f);
    p = -0.000200214257f;
    p = __fadd_rn(0.000100950558f,  __fmul_rn(p, t));
    p = __fadd_rn(0.00134934322f,   __fmul_rn(p, t));
    p = __fadd_rn(-0.00367342844f,  __fmul_rn(p, t));
    p = __fadd_rn(0.00573950773f,   __fmul_rn(p, t));
    p = __fadd_rn(-0.0076224613f,   __fmul_rn(p, t));
    p = __fadd_rn(0.00943887047f,   __fmul_rn(p, t));
    p = __fadd_rn(1.00167406f,      __fmul_rn(p, t));
    p = __fadd_rn(2.83297682f,      __fmul_rn(p, t));
  }
  float ei = __fmul_rn(p, u);
  float z  = __fmul_rn(__uint_as_float(0x3FB504F3u), ei);  // fp32 sqrt(2)
  // XLA LogisticExpander: 1/(1+exp(-x))
  float ez = expf(-z);
  return __fdiv_rn(1.0f, __fadd_rn(1.0f, ez));
}

__device__ __forceinline__ uint64_t shfl_xor_u64(uint64_t m, int lanemask) {
  uint32_t hi = (uint32_t)(m >> 32);
  uint32_t lo = (uint32_t)m;
  uint32_t ohi = __shfl_xor(hi, lanemask, 64);
  uint32_t olo = __shfl_xor(lo, lanemask, 64);
  return ((uint64_t)ohi << 32) | (uint64_t)olo;
}

__global__ __launch_bounds__(256)
void router_topk_kernel(float* __restrict__ out_idx, float* __restrict__ out_w) {
  const int t = blockIdx.x;    // one block per token
  const int e = threadIdx.x;   // expert id 0..255

  uint32_t bits = threefry_bits_k42((uint32_t)(t * NEXP + e));
  float s = score_from_bits(bits);

  // scores positive -> float bit order == uint order.
  // low byte (255-e): ties resolve to LOWER expert index (lax.top_k is stable).
  uint64_t cur = ((uint64_t)__float_as_uint(s) << 32) | (uint64_t)(255 - e);

  __shared__ uint64_t wred[4];
  __shared__ uint64_t winner_s;
  uint64_t tops[TOPK];

#pragma unroll
  for (int r = 0; r < TOPK; ++r) {
    uint64_t m = cur;
#pragma unroll
    for (int off = 32; off > 0; off >>= 1) {
      uint64_t o = shfl_xor_u64(m, off);
      if (o > m) m = o;
    }
    if ((e & 63) == 0) wred[e >> 6] = m;
    __syncthreads();
    if (e == 0) {
      uint64_t a = wred[0] > wred[1] ? wred[0] : wred[1];
      uint64_t b = wred[2] > wred[3] ? wred[2] : wred[3];
      winner_s = a > b ? a : b;
    }
    __syncthreads();
    uint64_t win = winner_s;
    tops[r] = win;
    if (cur == win) cur = 0;  // keys unique -> removes exactly the winner
    __syncthreads();
  }

  if (e == 0) {
    float sum = 0.0f;
#pragma unroll
    for (int r = 0; r < TOPK; ++r)
      sum = __fadd_rn(sum, __uint_as_float((uint32_t)(tops[r] >> 32)));
    sum = __fadd_rn(sum, 1e-8f);
#pragma unroll
    for (int r = 0; r < TOPK; ++r) {
      float sc  = __uint_as_float((uint32_t)(tops[r] >> 32));
      int   idx = 255 - (int)(tops[r] & 0xFFu);
      out_idx[t * TOPK + r] = (float)idx;   // tuple-concat promotes int32 idx to f32
      out_w[t * TOPK + r]   = __fdiv_rn(sc, sum);
    }
  }
}

extern "C" void kernel_launch(void* const* d_in, const int* in_sizes, int n_in,
                              void* d_out, int out_size, void* d_ws, size_t ws_size,
                              hipStream_t stream) {
  (void)d_in; (void)in_sizes; (void)n_in; (void)d_ws; (void)ws_size; (void)out_size;
  float* out_base = (float*)d_out;
  float* out_idx  = out_base;                 // [16384, 8] indices (as f32 values)
  float* out_w    = out_base + NTOK * TOPK;   // [16384, 8] weights
  router_topk_kernel<<<NTOK, 256, 0, stream>>>(out_idx, out_w);
}

// Round 4
// 18.431 us; speedup vs baseline: 4.4011x; 4.4011x over previous
//
#include <hip/hip_runtime.h>
#include <stdint.h>

// SimpleRouter: forward output depends ONLY on jax.random.normal(key(42), (16384,256)).
// (straight-through estimator erases the gate GEMM).
// Partitionable threefry (modern JAX default): bits[i] = y0^y1 of
// threefry2x32(key=(0,42), x0=0, x1=i).
//
// Key insight for speed: uniform->erfinv->sigmoid is monotone in (bits>>9),
// and ties in bits>>9 give bit-equal scores (reference breaks by index).
// So top-8 selection runs on u32 keys (bits & ~0x1FF) | (255-e) — order is
// IDENTICAL to lax.top_k on scores, including all tie cases. The transcendental
// score pipeline then runs on only the 8 winners per token.

#define NTOK 16384
#define NEXP 256
#define TOPK 8

__device__ __forceinline__ uint32_t rotl32(uint32_t v, int r) {
  return (v << r) | (v >> (32 - r));
}

// Partitionable-threefry 32-bit random word for flat index i, key (0, 42).
__device__ __forceinline__ uint32_t threefry_bits_k42(uint32_t i) {
  const uint32_t ks0 = 0u;
  const uint32_t ks1 = 42u;
  const uint32_t ks2 = 0x1BD11BF0u;  // 0 ^ 42 ^ 0x1BD11BDA
  uint32_t x0 = ks0;
  uint32_t x1 = i + ks1;
#define QR(R) x0 += x1; x1 = rotl32(x1, R); x1 ^= x0;
  QR(13) QR(15) QR(26) QR(6)
  x0 += ks1; x1 += ks2 + 1u;
  QR(17) QR(29) QR(16) QR(24)
  x0 += ks2; x1 += ks0 + 2u;
  QR(13) QR(15) QR(26) QR(6)
  x0 += ks0; x1 += ks1 + 3u;
  QR(17) QR(29) QR(16) QR(24)
  x0 += ks1; x1 += ks2 + 4u;
  QR(13) QR(15) QR(26) QR(6)
  x0 += ks2; x1 += ks0 + 5u;
#undef QR
  return x0 ^ x1;
}

// key>>9 == bits>>9. Rebuild sigmoid(sqrt(2)*erfinv(uniform(lo,1))) per XLA CPU
// lowering; explicit __fmul_rn/__fadd_rn forbid FMA contraction.
__device__ __forceinline__ float score_from_key(uint32_t key) {
  float f = __uint_as_float((key >> 9) | 0x3f800000u);
  f = __fadd_rn(f, -1.0f);                        // in [0,1)
  const float lo = __uint_as_float(0xBF7FFFFFu);  // nextafter(-1,0)
  float u = fmaxf(lo, __fadd_rn(__fmul_rn(f, 2.0f), lo));

  // w = -log1p(-u*u); XLA log1p: |x|<1e-4 ? x*(1-0.5x) : log(1+x)
  float negxx = -__fmul_rn(u, u);
  float w;
  if (fabsf(negxx) < 1e-4f) {
    w = -__fmul_rn(__fadd_rn(__fmul_rn(-0.5f, negxx), 1.0f), negxx);
  } else {
    w = -logf(__fadd_rn(1.0f, negxx));
  }

  float p;
  if (w < 5.0f) {
    float t = __fadd_rn(w, -2.5f);
    p = 2.81022636e-08f;
    p = __fadd_rn(3.43273939e-07f,  __fmul_rn(p, t));
    p = __fadd_rn(-3.5233877e-06f,  __fmul_rn(p, t));
    p = __fadd_rn(-4.39150654e-06f, __fmul_rn(p, t));
    p = __fadd_rn(0.00021858087f,   __fmul_rn(p, t));
    p = __fadd_rn(-0.00125372503f,  __fmul_rn(p, t));
    p = __fadd_rn(-0.00417768164f,  __fmul_rn(p, t));
    p = __fadd_rn(0.246640727f,     __fmul_rn(p, t));
    p = __fadd_rn(1.50140941f,      __fmul_rn(p, t));
  } else {
    float t = __fadd_rn(__fsqrt_rn(w), -3.0f);
    p = -0.000200214257f;
    p = __fadd_rn(0.000100950558f,  __fmul_rn(p, t));
    p = __fadd_rn(0.00134934322f,   __fmul_rn(p, t));
    p = __fadd_rn(-0.00367342844f,  __fmul_rn(p, t));
    p = __fadd_rn(0.00573950773f,   __fmul_rn(p, t));
    p = __fadd_rn(-0.0076224613f,   __fmul_rn(p, t));
    p = __fadd_rn(0.00943887047f,   __fmul_rn(p, t));
    p = __fadd_rn(1.00167406f,      __fmul_rn(p, t));
    p = __fadd_rn(2.83297682f,      __fmul_rn(p, t));
  }
  float ei = __fmul_rn(p, u);
  float z  = __fmul_rn(__uint_as_float(0x3FB504F3u), ei);  // fp32 sqrt(2)
  float ez = expf(-z);                                     // XLA logistic
  return __fdiv_rn(1.0f, __fadd_rn(1.0f, ez));
}

#define CSWAP(a, b) { uint32_t hi = (a) > (b) ? (a) : (b); \
                      uint32_t lo2 = (a) > (b) ? (b) : (a); (a) = hi; (b) = lo2; }

__global__ __launch_bounds__(256)
void router_topk_kernel(float* __restrict__ out_idx, float* __restrict__ out_w) {
  const int wave = threadIdx.x >> 6;          // 4 tokens per block
  const int lane = threadIdx.x & 63;
  const int t    = blockIdx.x * 4 + wave;

  // lane owns experts e0..e0+3 (lane-major so lower lane == lower expert)
  const int e0 = lane * 4;
  const uint32_t base = (uint32_t)t * NEXP + (uint32_t)e0;

  uint32_t k0 = (threefry_bits_k42(base + 0) & 0xFFFFFE00u) | (uint32_t)(255 - e0);
  uint32_t k1 = (threefry_bits_k42(base + 1) & 0xFFFFFE00u) | (uint32_t)(254 - e0);
  uint32_t k2 = (threefry_bits_k42(base + 2) & 0xFFFFFE00u) | (uint32_t)(253 - e0);
  uint32_t k3 = (threefry_bits_k42(base + 3) & 0xFFFFFE00u) | (uint32_t)(252 - e0);

  // lane-local descending sort (keys globally unique -> no tie handling needed)
  CSWAP(k0, k1) CSWAP(k2, k3) CSWAP(k0, k2) CSWAP(k1, k3) CSWAP(k1, k2)

  uint32_t my_key = 0;  // lane r (<8) keeps round-r winner
#pragma unroll
  for (int r = 0; r < TOPK; ++r) {
    uint32_t m = k0;
#pragma unroll
    for (int off = 1; off < 64; off <<= 1) {
      uint32_t o = (uint32_t)__shfl_xor((int)m, off, 64);
      m = m > o ? m : o;
    }
    if (lane == r) my_key = m;
    if (k0 == m) { k0 = k1; k1 = k2; k2 = k3; k3 = 0; }  // exactly one lane pops
  }

  // full score pipeline only for the 8 winners
  float sc = 0.0f;
  if (lane < TOPK) sc = score_from_key(my_key);

  // sum over lanes 0..7 (xor-closed octet)
  float s = sc;
  s = __fadd_rn(s, __shfl_xor(s, 1, 64));
  s = __fadd_rn(s, __shfl_xor(s, 2, 64));
  s = __fadd_rn(s, __shfl_xor(s, 4, 64));

  if (lane < TOPK) {
    int e = 255 - (int)(my_key & 0xFFu);
    out_idx[t * TOPK + lane] = (float)e;  // tuple-concat promotes int32 idx to f32
    out_w[t * TOPK + lane]   = __fdiv_rn(sc, __fadd_rn(s, 1e-8f));
  }
}

extern "C" void kernel_launch(void* const* d_in, const int* in_sizes, int n_in,
                              void* d_out, int out_size, void* d_ws, size_t ws_size,
                              hipStream_t stream) {
  (void)d_in; (void)in_sizes; (void)n_in; (void)d_ws; (void)ws_size; (void)out_size;
  float* out_base = (float*)d_out;
  float* out_idx  = out_base;                 // [16384, 8] indices (as f32 values)
  float* out_w    = out_base + NTOK * TOPK;   // [16384, 8] weights
  router_topk_kernel<<<NTOK / 4, 256, 0, stream>>>(out_idx, out_w);
}